// Round 8
// baseline (466.699 us; speedup 1.0000x reference)
//
#include <hip/hip_runtime.h>
#include <hip/hip_bf16.h>
#include <stdint.h>

// ---------------------------------------------------------------------------
// SmallTransformerBlock on MI355X (gfx950)  — Round 16 (R15 resubmit)
//   B=4, T=2048, D=1024, FF=4096, full-D attention, scale = sqrt(128)
// R15 bench died with "container failed twice" (infra; same signature as
// R9, which ran clean on identical resubmit). Code re-audited: vector
// alignment ✓, transpose index identity ✓, no barrier divergence ✓.
// R14 -> R15/R16 (G13 vectorization of the transpose paths; GEMMs untouched):
//   * prep weight transposes: f32 loads 4B/lane -> float4 16B/lane; bf16
//     stores 2B/lane -> ushort4 8B/lane (LDS 32x33 tile, reads <=2-way).
//   * attn_mid vT transpose: ushort 2B/lane -> ushort4 8B/lane both sides.
//   * Everything else bit-identical to the 441.3us-measured R14 base.
// ---------------------------------------------------------------------------

typedef __bf16 bf16x8 __attribute__((ext_vector_type(8)));
typedef float f32x4 __attribute__((ext_vector_type(4)));

__device__ __forceinline__ unsigned short f2b(float f) {
    __hip_bfloat16 h = __float2bfloat16(f);
    unsigned short u;
    __builtin_memcpy(&u, &h, 2);
    return u;
}

__device__ __forceinline__ float b2f(unsigned short u) {
    __hip_bfloat16 h;
    __builtin_memcpy(&h, &u, 2);
    return __bfloat162float(h);
}

__device__ __forceinline__ void async_copy16(const unsigned short* g, unsigned short* l) {
    __builtin_amdgcn_global_load_lds((__attribute__((address_space(1))) void*)(g),
                                     (__attribute__((address_space(3))) void*)(l),
                                     16, 0, 0);
}

// ---------------------------------------------------------------------------
// gemm_tile: one 128x128 output tile of C = A @ Bt^T  (A,Bt bf16, K-contig).
// MODE 0: +bias                  (fused QKV)
// MODE 1: exp(acc*scale-16) + fused fp32 row-sum atomicAdd  (scores)
// MODE 2: /rowsum[z*sR + row]    (ctx = P @ V, normalized)
// MODE 3: +bias, +resid(bf16)    (o-proj, FFN2)
// MODE 4: +bias, relu            (FFN1)
// ---------------------------------------------------------------------------
template <int MODE, int BK>
__device__ __forceinline__ void gemm_tile(
    unsigned short* lds_us,
    const unsigned short* __restrict__ A, int lda,
    const unsigned short* __restrict__ Bt, int ldb,
    unsigned short* __restrict__ Cv, int ldc,
    const float* __restrict__ bias,
    const unsigned short* __restrict__ resid, int ldr,
    float* __restrict__ rowsum,
    int K, long sA, long sB, long sC, long sR, float scale,
    int bx, int by, int z)
{
    constexpr bool HAS_BIAS  = (MODE == 0 || MODE == 3 || MODE == 4);
    constexpr bool HAS_RESID = (MODE == 3);
    constexpr bool RELU      = (MODE == 4);
    constexpr bool EXPW      = (MODE == 1);
    constexpr bool ROWSCALE  = (MODE == 2);
    constexpr int  CPR = BK / 8;    // 16B chunks per row
    constexpr int  P   = BK / 16;   // staging groups of 256 chunks per operand
    constexpr int  KS  = BK / 32;   // 32-k steps per tile

    unsigned short* ldsA = lds_us;
    unsigned short* ldsB = lds_us + 128 * BK;

    const unsigned short* Ab = A + (long)z * sA + (long)by * 128 * lda;
    const unsigned short* Bb = Bt + (long)z * sB + (long)bx * 128 * ldb;

    const int tid  = threadIdx.x;
    const int lane = tid & 63;
    const int wid  = tid >> 6;
    const int wr   = wid >> 1;
    const int wc   = wid & 1;

    f32x4 acc[4][4] = {};

    long offA[P], offB[P];
    unsigned short* dA[P];
    unsigned short* dB[P];
#pragma unroll
    for (int p = 0; p < P; ++p) {
        const int s = p * 256 + tid;
        const int r = s / CPR;
        const int c = ((s & (CPR - 1)) ^ (r & (CPR - 1))) * 8;
        offA[p] = (long)r * lda + c;
        offB[p] = (long)r * ldb + c;
        dA[p] = ldsA + (p * 256 + wid * 64) * 8;
        dB[p] = ldsB + (p * 256 + wid * 64) * 8;
    }

    const int kq = lane >> 4;
    const int rr = lane & 15;

    for (int k0 = 0; k0 < K; k0 += BK) {
        __syncthreads();
#pragma unroll
        for (int p = 0; p < P; ++p) {
            async_copy16(Ab + offA[p] + k0, dA[p]);
            async_copy16(Bb + offB[p] + k0, dB[p]);
        }
        __syncthreads();

#pragma unroll
        for (int ks = 0; ks < KS; ++ks) {
            const int st = (ks * 4 + kq) ^ (rr & (CPR - 1));
            bf16x8 af[4], bfr[4];
#pragma unroll
            for (int mi = 0; mi < 4; ++mi)
                af[mi] = *(const bf16x8*)(ldsA + (wr * 64 + mi * 16 + rr) * BK + st * 8);
#pragma unroll
            for (int ni = 0; ni < 4; ++ni)
                bfr[ni] = *(const bf16x8*)(ldsB + (wc * 64 + ni * 16 + rr) * BK + st * 8);
#pragma unroll
            for (int mi = 0; mi < 4; ++mi)
#pragma unroll
                for (int ni = 0; ni < 4; ++ni)
                    acc[mi][ni] = __builtin_amdgcn_mfma_f32_16x16x32_bf16(af[mi], bfr[ni], acc[mi][ni], 0, 0, 0);
        }
    }

    // Epilogue. C/D layout: col = lane&15, row = (lane>>4)*4 + reg
    const long zC = (long)z * sC;
    const int colb = bx * 128 + wc * 64 + rr;
    const int rowb = by * 128 + wr * 64 + kq * 4;
    if constexpr (EXPW) {
        // exp + fused row-sum: per (mi,r) the 16 rr-lanes x 4 n-frags cover
        // 64 cols of one row. fp32 partial, shfl_xor reduce over the 16-lane
        // group, 1 atomicAdd per row per wave.
#pragma unroll
        for (int mi = 0; mi < 4; ++mi) {
#pragma unroll
            for (int r = 0; r < 4; ++r) {
                const int row = rowb + mi * 16 + r;
                float part = 0.0f;
#pragma unroll
                for (int ni = 0; ni < 4; ++ni) {
                    const int col = colb + ni * 16;
                    float v = __expf(acc[mi][ni][r] * scale - 16.0f);
                    part += v;
                    Cv[zC + (long)row * ldc + col] = f2b(v);
                }
                part += __shfl_xor(part, 1);
                part += __shfl_xor(part, 2);
                part += __shfl_xor(part, 4);
                part += __shfl_xor(part, 8);
                if (rr == 0) atomicAdd(&rowsum[(long)z * sR + row], part);
            }
        }
    } else {
#pragma unroll
        for (int mi = 0; mi < 4; ++mi) {
            float inv_r[4];
            if constexpr (ROWSCALE) {
#pragma unroll
                for (int r = 0; r < 4; ++r)
                    inv_r[r] = 1.0f / rowsum[(long)z * sR + (rowb + mi * 16 + r)];
            }
#pragma unroll
            for (int ni = 0; ni < 4; ++ni) {
                const int col = colb + ni * 16;
                float bv = 0.0f;
                if constexpr (HAS_BIAS) bv = bias[col];
#pragma unroll
                for (int r = 0; r < 4; ++r) {
                    const int row = rowb + mi * 16 + r;
                    float v = acc[mi][ni][r] * scale + bv;
                    if constexpr (ROWSCALE) v *= inv_r[r];
                    if constexpr (HAS_RESID) v += b2f(resid[(long)z * sR + (long)row * ldr + col]);
                    if constexpr (RELU) v = v > 0.0f ? v : 0.0f;
                    Cv[zC + (long)row * ldc + col] = f2b(v);
                }
            }
        }
    }
}

// ---------------------------------------------------------------------------
// gemm_bt: standalone launch wrapper. grid (N/128, M/128, batch), block 256.
// ---------------------------------------------------------------------------
template <int MODE, int BK>
__launch_bounds__(256, 2)
__global__ void gemm_bt(const unsigned short* __restrict__ A, int lda,
                        const unsigned short* __restrict__ Bt, int ldb,
                        unsigned short* __restrict__ Cv, int ldc,
                        const float* __restrict__ bias,
                        const unsigned short* __restrict__ resid, int ldr,
                        float* __restrict__ rowsum,
                        int K, long sA, long sB, long sC, long sR, float scale) {
    __shared__ unsigned short lds_us[256 * BK];  // A[128][BK] + B[128][BK]

    // XCD-aware swizzle (ny % 8 == 0 for all our grids)
    const int nx = (int)gridDim.x, ny = (int)gridDim.y;
    int bx, by;
    if ((ny & 7) == 0) {
        const int n     = (int)blockIdx.y * nx + (int)blockIdx.x;
        const int xcd   = n & 7;
        const int slot  = n >> 3;
        const int bandh = ny >> 3;
        by = xcd * bandh + (slot % bandh);
        bx = slot / bandh;
    } else {
        bx = (int)blockIdx.x;
        by = (int)blockIdx.y;
    }

    gemm_tile<MODE, BK>(lds_us, A, lda, Bt, ldb, Cv, ldc, bias, resid, ldr,
                        rowsum, K, sA, sB, sC, sR, scale, bx, by, (int)blockIdx.z);
}

// ---------------------------------------------------------------------------
// attn_mid: one launch for everything that depends only on QKV:
//   blocks [0,1024)     scores tiles: P = exp(q@k^T*scale-16) + rowsum
//   blocks [1024,9216)  V-transpose 32x32 tiles (vectorized ushort4 both
//                       sides; LDS 32x33 tile)
// block = 256 threads, LDS 32 KiB.
// ---------------------------------------------------------------------------
__launch_bounds__(256, 2)
__global__ void attn_mid(const unsigned short* __restrict__ qkv,
                         unsigned short* __restrict__ pr,
                         unsigned short* __restrict__ vT,
                         float* __restrict__ rowsum) {
    __shared__ unsigned short lds_us[256 * 64];
    const int j = blockIdx.x;
    if (j < 1024) {
        const int z    = j >> 8;
        const int n    = j & 255;
        const int xcd  = n & 7;          // nx=16, ny=16 -> bandh = 2
        const int slot = n >> 3;
        const int by   = xcd * 2 + (slot & 1);
        const int bx   = slot >> 1;
        gemm_tile<1, 64>(lds_us, qkv, 3072, qkv + 1024, 3072, pr, 2048,
                         nullptr, nullptr, 0, rowsum,
                         1024, (long)2048 * 3072, (long)2048 * 3072,
                         (long)2048 * 2048, 2048,
                         0.08838834764831845f, bx, by, z);
    } else {
        // vT[d][t] = V[t][d].  tile[i][jj] = src[(by+i)*3072 + bx+jj].
        const int t   = j - 1024;
        const int z   = t >> 11;
        const int rem = t & 2047;
        const int bx  = (rem & 31) * 32;   // col base in src (D dim)
        const int by  = (rem >> 5) * 32;   // row base in src (T dim)
        const unsigned short* src = qkv + 2048 + (long)z * 2048 * 3072;
        unsigned short* dst = vT + (long)z * 1024 * 2048;
        unsigned short (*tile)[33] = (unsigned short(*)[33])lds_us;
        const int row = threadIdx.x >> 3;       // 0..31
        const int c4  = (threadIdx.x & 7) * 4;  // 0,4,..,28
        const ushort4 v = *(const ushort4*)(src + (long)(by + row) * 3072 + bx + c4);
        tile[row][c4 + 0] = v.x; tile[row][c4 + 1] = v.y;
        tile[row][c4 + 2] = v.z; tile[row][c4 + 3] = v.w;
        __syncthreads();
        ushort4 o;
        o.x = tile[c4 + 0][row]; o.y = tile[c4 + 1][row];
        o.z = tile[c4 + 2][row]; o.w = tile[c4 + 3][row];
        *(ushort4*)(dst + (long)(bx + row) * 2048 + by + c4) = o;
    }
}

// ---------------------------------------------------------------------------
// prep: all input preprocessing in ONE launch (job table by blockIdx.x):
//   [0,4096)      wq/wk/wv/wo f32 -> bf16 transposed into wqT (contiguous)
//   [4096,8192)   w1 [1024][4096] -> w1T [4096][1024]
//   [8192,12288)  w2 [4096][1024] -> w2T [1024][4096]
//   [12288,20480) x f32 -> xb bf16
//   [20480,20492) bcat = concat(bq, bk, bv)
//   [20492,20524) rsum[0:8192) = 0
// Transposes vectorized: float4 loads (16B/lane), ushort4 stores (8B/lane),
// LDS 32x33 f32 tile (stride-33 -> column reads <=2-way conflicted = free).
// ---------------------------------------------------------------------------
__global__ void prep(const float* __restrict__ wq, const float* __restrict__ wk,
                     const float* __restrict__ wv, const float* __restrict__ wo,
                     unsigned short* __restrict__ wqT,
                     const float* __restrict__ w1, unsigned short* __restrict__ w1T,
                     const float* __restrict__ w2, unsigned short* __restrict__ w2T,
                     const float* __restrict__ x, unsigned short* __restrict__ xb,
                     const float* __restrict__ bq, const float* __restrict__ bk,
                     const float* __restrict__ bv, float* __restrict__ bcat,
                     float* __restrict__ rsum) {
    const int job = blockIdx.x;
    const int tid = threadIdx.x;
    if (job < 12288) {
        __shared__ float tile[32][33];
        const int row = tid >> 3;       // 0..31
        const int c4  = (tid & 7) * 4;  // 0,4,..,28
        const float* src;
        unsigned short* dst;
        int R, C, bx, by;
        if (job < 4096) {
            const int m = job >> 10, t = job & 1023;
            src = (m == 0) ? wq : (m == 1) ? wk : (m == 2) ? wv : wo;
            dst = wqT + (long)m * 1024 * 1024;
            R = 1024; C = 1024;
            bx = (t & 31) * 32; by = (t >> 5) * 32;
        } else if (job < 8192) {
            const int t = job - 4096;
            src = w1; dst = w1T; R = 1024; C = 4096;
            bx = (t & 127) * 32; by = (t >> 7) * 32;
        } else {
            const int t = job - 8192;
            src = w2; dst = w2T; R = 4096; C = 1024;
            bx = (t & 31) * 32; by = (t >> 5) * 32;
        }
        const float4 v = *(const float4*)(src + (long)(by + row) * C + bx + c4);
        tile[row][c4 + 0] = v.x; tile[row][c4 + 1] = v.y;
        tile[row][c4 + 2] = v.z; tile[row][c4 + 3] = v.w;
        __syncthreads();
        // dst[(bx+row)][by+c4+k] = src[by+c4+k][bx+row] = tile[c4+k][row]
        ushort4 o;
        o.x = f2b(tile[c4 + 0][row]); o.y = f2b(tile[c4 + 1][row]);
        o.z = f2b(tile[c4 + 2][row]); o.w = f2b(tile[c4 + 3][row]);
        *(ushort4*)(dst + (long)(bx + row) * R + by + c4) = o;
    } else if (job < 20480) {
        const long i = ((long)(job - 12288) * 256 + tid) * 4;
        const float4 v = *(const float4*)(x + i);
        ushort4 o;
        o.x = f2b(v.x); o.y = f2b(v.y); o.z = f2b(v.z); o.w = f2b(v.w);
        *(ushort4*)(xb + i) = o;
    } else if (job < 20492) {
        const int i = (job - 20480) * 256 + tid;  // 0..3071
        bcat[i] = (i < 1024) ? bq[i] : (i < 2048) ? bk[i - 1024] : bv[i - 2048];
    } else {
        const int i = (job - 20492) * 256 + tid;  // 0..8191
        rsum[i] = 0.0f;
    }
}

// ------------------ LayerNorm (1024 cols), bf16 input ----------------------
template <bool OUT_F32>
__global__ void layernorm_bf16(const unsigned short* __restrict__ in, float* outf,
                               unsigned short* outb,
                               const float* __restrict__ g, const float* __restrict__ b) {
    const long row = blockIdx.x;
    const int t = threadIdx.x;
    const ushort4 u = ((const ushort4*)(in + row * 1024))[t];
    float4 v;
    v.x = b2f(u.x); v.y = b2f(u.y); v.z = b2f(u.z); v.w = b2f(u.w);
    float s = v.x + v.y + v.z + v.w;
    float q = v.x * v.x + v.y * v.y + v.z * v.z + v.w * v.w;
#pragma unroll
    for (int off = 32; off > 0; off >>= 1) {
        s += __shfl_down(s, off);
        q += __shfl_down(q, off);
    }
    __shared__ float red[8];
    if ((t & 63) == 0) { red[t >> 6] = s; red[4 + (t >> 6)] = q; }
    __syncthreads();
    s = red[0] + red[1] + red[2] + red[3];
    q = red[4] + red[5] + red[6] + red[7];
    const float mean = s * (1.0f / 1024.0f);
    const float var  = q * (1.0f / 1024.0f) - mean * mean;
    const float inv  = rsqrtf(var + 1e-5f);
    const float4 gg = ((const float4*)g)[t];
    const float4 bb = ((const float4*)b)[t];
    float4 o;
    o.x = (v.x - mean) * inv * gg.x + bb.x;
    o.y = (v.y - mean) * inv * gg.y + bb.y;
    o.z = (v.z - mean) * inv * gg.z + bb.z;
    o.w = (v.w - mean) * inv * gg.w + bb.w;
    if constexpr (OUT_F32) {
        ((float4*)(outf + row * 1024))[t] = o;
    } else {
        ushort4 ob;
        ob.x = f2b(o.x); ob.y = f2b(o.y); ob.z = f2b(o.z); ob.w = f2b(o.w);
        ((ushort4*)(outb + row * 1024))[t] = ob;
    }
}

// ---------------------------------------------------------------------------
extern "C" void kernel_launch(void* const* d_in, const int* in_sizes, int n_in,
                              void* d_out, int out_size, void* d_ws, size_t ws_size,
                              hipStream_t stream) {
    (void)in_sizes; (void)n_in; (void)out_size; (void)ws_size;
    const float* x   = (const float*)d_in[0];
    const float* wq  = (const float*)d_in[1];
    const float* bq  = (const float*)d_in[2];
    const float* wk  = (const float*)d_in[3];
    const float* bk  = (const float*)d_in[4];
    const float* wv  = (const float*)d_in[5];
    const float* bv  = (const float*)d_in[6];
    const float* wo  = (const float*)d_in[7];
    const float* bo  = (const float*)d_in[8];
    const float* w1  = (const float*)d_in[9];
    const float* b1  = (const float*)d_in[10];
    const float* w2  = (const float*)d_in[11];
    const float* b2  = (const float*)d_in[12];
    const float* g1  = (const float*)d_in[13];
    const float* be1 = (const float*)d_in[14];
    const float* g2  = (const float*)d_in[15];
    const float* be2 = (const float*)d_in[16];

    const int D = 1024, FF = 4096, T = 2048, M = 8192;
    const size_t MB = 1ull << 20;
    char* w = (char*)d_ws;
    unsigned short* wqT = (unsigned short*)(w + 0 * MB);    // [3072+1024][1024] wcat+woT
    unsigned short* woT = (unsigned short*)(w + 6 * MB);    // [1024][1024] (= wqT+3*D*D)
    unsigned short* w1T = (unsigned short*)(w + 8 * MB);    // [4096][1024]
    unsigned short* w2T = (unsigned short*)(w + 16 * MB);   // [1024][4096]
    unsigned short* xb  = (unsigned short*)(w + 24 * MB);   // [8192][1024]
    unsigned short* qkv = (unsigned short*)(w + 40 * MB);   // [8192][3072]
    float*          bcat = (float*)(w + 88 * MB);           // [3072], dead before vT
    unsigned short* vT  = (unsigned short*)(w + 88 * MB);   // [4][1024][2048]
    unsigned short* pr  = (unsigned short*)(w + 104 * MB);  // [4][2048][2048] bf16
    unsigned short* ctxb = (unsigned short*)(w + 136 * MB); // [8192][1024] bf16
    // rsum aliases t0's first 32 KB: rsum lifetime = [prep zero .. ctx read];
    // t0 born at oproj (strictly after ctx) -> disjoint.
    float*          rsum = (float*)(w + 152 * MB);          // [8192] fp32
    unsigned short* t0  = (unsigned short*)(w + 152 * MB);  // [8192][1024] bf16
    unsigned short* x1b = (unsigned short*)(w + 56 * MB);   // [8192][1024] bf16
    unsigned short* h   = (unsigned short*)(w + 88 * MB);   // [8192][4096] bf16
    unsigned short* y   = (unsigned short*)(w + 168 * MB);  // [8192][1024] bf16

    // ---- all preprocessing in one launch
    prep<<<20524, 256, 0, stream>>>(wq, wk, wv, wo, wqT, w1, w1T, w2, w2T,
                                    x, xb, bq, bk, bv, bcat, rsum);

    // Fused QKV projection: [8192][3072] = xb @ wcat^T + bcat (24x64 grid)
    gemm_bt<0, 64><<<dim3(24, 64, 1), 256, 0, stream>>>(xb, D, wqT, D, qkv, 3 * D, bcat,
                                                        nullptr, 0, nullptr,
                                                        D, 0, 0, 0, 0, 1.0f);

    // scores (exp + fused rowsum) AND V-transpose in one launch
    attn_mid<<<9216, 256, 0, stream>>>(qkv, pr, vT, rsum);

    // ctx = (P @ v) / rsum   (512 blocks -> BK=128)
    gemm_bt<2, 128><<<dim3(8, 16, 4), 256, 0, stream>>>(pr, T, vT, T, ctxb, D,
                                                        nullptr, nullptr, 0, rsum,
                                                        T,
                                                        (long)T * T, (long)D * T, (long)T * D, T, 1.0f);

    // o-projection + residual (bf16 xb), bf16 out (512 blocks -> BK=128)
    gemm_bt<3, 128><<<dim3(8, 64, 1), 256, 0, stream>>>(ctxb, D, woT, D, t0, D, bo, xb, D,
                                                        nullptr, D, 0, 0, 0, 0, 1.0f);

    // LN1 (bf16 in) -> bf16 x1b (FFN input + FFN2 residual)
    layernorm_bf16<false><<<8192, 256, 0, stream>>>(t0, nullptr, x1b, g1, be1);

    // FFN1 (2048 blocks -> BK=64)
    gemm_bt<4, 64><<<dim3(32, 64, 1), 256, 0, stream>>>(x1b, D, w1T, D, h, FF, b1, nullptr, 0,
                                                        nullptr, D, 0, 0, 0, 0, 1.0f);
    // FFN2 (512 blocks -> BK=128)
    gemm_bt<3, 128><<<dim3(8, 64, 1), 256, 0, stream>>>(h, FF, w2T, FF, y, D, b2, x1b, D,
                                                        nullptr, FF, 0, 0, 0, 0, 1.0f);

    // LN2 (bf16 in) -> output (fp32)
    layernorm_bf16<true><<<8192, 256, 0, stream>>>(y, (float*)d_out, nullptr, g2, be2);
}